// Round 3
// baseline (162.821 us; speedup 1.0000x reference)
//
#include <hip/hip_runtime.h>
#include <hip/hip_bf16.h>
#include <math.h>

#define IMG 512
#define TW 64                     // output tile width
#define TH 32                     // output tile height
#define NTX 8                     // 512/64
#define NTY 16                    // 512/32
#define NIMG 48                   // 16*3
#define NBLOCKS (NTX * NTY * NIMG)   // 6144
#define NPIX (16LL * 3 * 512 * 512)

#define C1F 0.0001f
#define C2F 0.0009f

// R3: NO LDS staging. The old sbuf had zero intra-block reuse (each element
// fed exactly one A-fragment), so each lane now loads its 8-pixel fragment
// (row rg*16+n16, cols c00a+w*16+q*8..+8) straight from global as 2 float4s
// per image, converts to bf16 in-register, and rebuilds the product channels.
// This removes the stage->vmcnt(0)->barrier phase convoy that pinned HBM BW
// at ~2 TB/s across R0-R2 regardless of occupancy (33%->62% => no change).
// Intra-block halo overlap (~1.8x demand) is served by L2 (~12 TB/s needed
// vs 34.5 achievable); HBM FETCH stays ~compulsory.
// Coalescing: 4 quads of the same row cover 128 contiguous bytes; lines are
// fully consumed. Per-lane 32B units are all-in or all-out of [0,512) so OOB
// is a single predicate per (lane, rg) -- matches reference zero padding.

typedef __attribute__((ext_vector_type(4))) short short4v;
typedef __attribute__((ext_vector_type(8))) short short8;
typedef __attribute__((ext_vector_type(4))) float float4v;
typedef __attribute__((ext_vector_type(2))) unsigned uint2v;
typedef __attribute__((ext_vector_type(4))) unsigned uint4v;

// 16x16x16 bf16 MFMA (device-verified _1k builtin on gfx950; host parse stub).
__device__ __forceinline__ float4v mfma16(short4v a, short4v b, float4v c) {
#if defined(__HIP_DEVICE_COMPILE__)
    return __builtin_amdgcn_mfma_f32_16x16x16bf16_1k(a, b, c, 0, 0, 0);
#else
    return c;   // host stub — never executed
#endif
}

// Gaussian window (sigma=1.5, ws=11), normalized (double-derived literals).
#define GW0 0.00102838f
#define GW1 0.00759877f
#define GW2 0.03600077f
#define GW3 0.10936069f
#define GW4 0.21300539f
#define GW5 0.26601172f

__device__ __forceinline__ unsigned short f2bf(float f) {
    unsigned u = __builtin_bit_cast(unsigned, f);
    u += 0x7FFF + ((u >> 16) & 1);            // RNE
    return (unsigned short)(u >> 16);
}
__device__ __forceinline__ unsigned pk2(float a, float b) {
    __hip_bfloat162 h = __float22bfloat162_rn(make_float2(a, b));
    unsigned u;
    __builtin_memcpy(&u, &h, 4);
    return u;
}

__global__ __launch_bounds__(256, 6)
void ssim_tile_kernel(const float* __restrict__ xg, const float* __restrict__ yg,
                      float* __restrict__ partials) {
    __shared__ unsigned short gwtbl[16];            // bf16 taps, [11..15]=0
    __shared__ float red[8];

    const int tid  = threadIdx.x;
    const int lane = tid & 63;
    const int w    = tid >> 6;        // wave 0..3 = colgroup
    const int q    = lane >> 4;       // quad 0..3
    const int n16  = lane & 15;

    const int img = blockIdx.z;
    const int r00  = blockIdx.y * TH - 5;   // global row of staged-coords row 0
    const int c00a = blockIdx.x * TW - 8;   // global col of staged-coords col 0
    const float* __restrict__ xi = xg + (size_t)img * (IMG * IMG);
    const float* __restrict__ yi = yg + (size_t)img * (IMG * IMG);

    // ---- bf16 Gaussian tap table (compile-time-folded constants) ----
    if (tid < 16) {
        const float gwf[11] = {GW0, GW1, GW2, GW3, GW4, GW5, GW4, GW3, GW2, GW1, GW0};
        unsigned short v = 0;
        #pragma unroll
        for (int t = 0; t < 11; ++t)
            if (tid == t) v = f2bf(gwf[t]);
        gwtbl[tid] = v;
    }
    __syncthreads();   // publish gwtbl; the only pre-compute barrier (no mem in flight)

    // ---- B fragments from gwtbl (OOB index clamps to >=11 -> 0) ----
    // h (K=32): Bh[k][n] = g[k-n-3], k = q*8+j
    // v chunk0 (K=16): Bv0[k][n] = g[k-n]; chunk1: Bv1[k][n] = g[k+16-n]
    short8 bh;
    short4v bv0, bv1;
    {
        int baseh = q * 8 - n16 - 3;
        #pragma unroll
        for (int j = 0; j < 8; ++j)
            bh[j] = (short)gwtbl[min((unsigned)(baseh + j), 15u)];
        int base0 = q * 4 - n16, base1 = q * 4 + 16 - n16;
        #pragma unroll
        for (int j = 0; j < 4; ++j) {
            bv0[j] = (short)gwtbl[min((unsigned)(base0 + j), 15u)];
            bv1[j] = (short)gwtbl[min((unsigned)(base1 + j), 15u)];
        }
    }

    // ---- H-conv via MFMA, fragments loaded DIRECTLY from global ----
    // Lane (w,q,n16), rg: 8 pixels at global (r00+row, c00a+16w+8q+[0,8)),
    // row = min(rg*16+n16, 41) (rows 42..47 feed only zero v-taps).
    // 32B col unit is 8-aligned => fully in/out of [0,512): one predicate.
    const int cbase = c00a + w * 16 + q * 8;
    const bool colok = (unsigned)cbase < 512u;
    const float4v zero4 = {0.f, 0.f, 0.f, 0.f};
    const float4 zf = make_float4(0.f, 0.f, 0.f, 0.f);

    uint2v d1[3][4];
    float l1_loc = 0.f;
    #pragma unroll
    for (int rg = 0; rg < 3; ++rg) {
        const int srow = rg * 16 + n16;            // staged-coords row (pre-clamp)
        const int row  = (rg == 2) ? min(srow, 41) : srow;
        const int gr   = r00 + row;
        const bool ok  = colok && (unsigned)gr < 512u;
        float4 xf0 = zf, xf1 = zf, yf0 = zf, yf1 = zf;
        if (ok) {
            const size_t o = (size_t)gr * IMG + cbase;
            xf0 = *(const float4*)(xi + o);
            xf1 = *(const float4*)(xi + o + 4);
            yf0 = *(const float4*)(yi + o);
            yf1 = *(const float4*)(yi + o + 4);
        }
        // bf16 fragments: x, y, x^2+y^2, x*y (products from raw floats,
        // rounded once — same error class as R2, absmax was insensitive).
        uint4v ux = (uint4v){pk2(xf0.x, xf0.y), pk2(xf0.z, xf0.w),
                             pk2(xf1.x, xf1.y), pk2(xf1.z, xf1.w)};
        uint4v uy = (uint4v){pk2(yf0.x, yf0.y), pk2(yf0.z, yf0.w),
                             pk2(yf1.x, yf1.y), pk2(yf1.z, yf1.w)};
        uint4v u2 = (uint4v){
            pk2(fmaf(xf0.x, xf0.x, yf0.x * yf0.x), fmaf(xf0.y, xf0.y, yf0.y * yf0.y)),
            pk2(fmaf(xf0.z, xf0.z, yf0.z * yf0.z), fmaf(xf0.w, xf0.w, yf0.w * yf0.w)),
            pk2(fmaf(xf1.x, xf1.x, yf1.x * yf1.x), fmaf(xf1.y, xf1.y, yf1.y * yf1.y)),
            pk2(fmaf(xf1.z, xf1.z, yf1.z * yf1.z), fmaf(xf1.w, xf1.w, yf1.w * yf1.w))};
        uint4v u3 = (uint4v){
            pk2(xf0.x * yf0.x, xf0.y * yf0.y), pk2(xf0.z * yf0.z, xf0.w * yf0.w),
            pk2(xf1.x * yf1.x, xf1.y * yf1.y), pk2(xf1.z * yf1.z, xf1.w * yf1.w)};

        float4v d;
        d = __builtin_amdgcn_mfma_f32_16x16x32_bf16(
                __builtin_bit_cast(short8, ux), bh, zero4, 0, 0, 0);
        d1[rg][0] = (uint2v){pk2(d[0], d[1]), pk2(d[2], d[3])};
        d = __builtin_amdgcn_mfma_f32_16x16x32_bf16(
                __builtin_bit_cast(short8, uy), bh, zero4, 0, 0, 0);
        d1[rg][1] = (uint2v){pk2(d[0], d[1]), pk2(d[2], d[3])};
        d = __builtin_amdgcn_mfma_f32_16x16x32_bf16(
                __builtin_bit_cast(short8, u2), bh, zero4, 0, 0, 0);
        d1[rg][2] = (uint2v){pk2(d[0], d[1]), pk2(d[2], d[3])};
        d = __builtin_amdgcn_mfma_f32_16x16x32_bf16(
                __builtin_bit_cast(short8, u3), bh, zero4, 0, 0, 0);
        d1[rg][3] = (uint2v){pk2(d[0], d[1]), pk2(d[2], d[3])};

        // L1 ownership: q in {1,2} (pixels [16w+8,16w+24) -> [8,72) over w)
        // and interior rows srow in [5,36] — tiles the 64x32 output exactly
        // once; owned lanes are never OOB and never row-clamped.
        if ((unsigned)(q - 1) <= 1u && (unsigned)(srow - 5) <= 31u)
            l1_loc += fabsf(xf0.x - yf0.x) + fabsf(xf0.y - yf0.y)
                    + fabsf(xf0.z - yf0.z) + fabsf(xf0.w - yf0.w)
                    + fabsf(xf1.x - yf1.x) + fabsf(xf1.y - yf1.y)
                    + fabsf(xf1.z - yf1.z) + fabsf(xf1.w - yf1.w);
    }

    // ---- V-conv: acc = D1[rgp]·Bv0 + D1[rgp+1]·Bv1 (two chained x16 MFMAs).
    //      D output: lane (q,n16) = out row rgp*16+n16, out cols w*16+q*4+r. ----
    float ssim_loc = 0.f;
    #pragma unroll
    for (int rgp = 0; rgp < 2; ++rgp) {
        float4v acc4[4];
        #pragma unroll
        for (int ch = 0; ch < 4; ++ch) {
            short4v a1 = __builtin_bit_cast(short4v, d1[rgp + 1][ch]);
            short4v a0 = __builtin_bit_cast(short4v, d1[rgp][ch]);
            acc4[ch] = mfma16(a0, bv0, mfma16(a1, bv1, zero4));
        }
        // SSIM: p=mu1*mu2, s=mu1^2+mu2^2, e=E11+E22 (conv of x^2+y^2)
        #pragma unroll
        for (int r = 0; r < 4; ++r) {
            float mu1 = acc4[0][r], mu2 = acc4[1][r];
            float e   = acc4[2][r], e12 = acc4[3][r];
            float p = mu1 * mu2;
            float s = fmaf(mu1, mu1, mu2 * mu2);
            float num1 = fmaf(2.f, p, C1F);
            float num2 = fmaf(2.f, e12 - p, C2F);
            float den1 = s + C1F;
            float den2 = (e - s) + C2F;
            ssim_loc = fmaf(num1 * num2, __builtin_amdgcn_rcpf(den1 * den2), ssim_loc);
        }
    }

    // ---- Block reduction ----
    #pragma unroll
    for (int off = 32; off > 0; off >>= 1) {
        ssim_loc += __shfl_down(ssim_loc, off);
        l1_loc   += __shfl_down(l1_loc, off);
    }
    if (lane == 0) {
        red[w] = ssim_loc;
        red[4 + w] = l1_loc;
    }
    __syncthreads();
    if (tid == 0) {
        float ss = red[0] + red[1] + red[2] + red[3];
        float ll = red[4] + red[5] + red[6] + red[7];
        int bid = blockIdx.x + NTX * (blockIdx.y + NTY * blockIdx.z);
        partials[bid] = ss;
        partials[NBLOCKS + bid] = ll;
    }
}

__global__ __launch_bounds__(1024)
void finalize_kernel(const float* __restrict__ partials, float* __restrict__ out) {
    __shared__ double rs[16], rl[16];
    const int tid = threadIdx.x;
    double ss = 0.0, ll = 0.0;
    for (int i = tid; i < NBLOCKS; i += 1024) {
        ss += (double)partials[i];
        ll += (double)partials[NBLOCKS + i];
    }
    #pragma unroll
    for (int off = 32; off > 0; off >>= 1) {
        ss += __shfl_down(ss, off);
        ll += __shfl_down(ll, off);
    }
    int wave = tid >> 6, lane = tid & 63;
    if (lane == 0) { rs[wave] = ss; rl[wave] = ll; }
    __syncthreads();
    if (tid == 0) {
        double sst = 0.0, llt = 0.0;
        #pragma unroll
        for (int w = 0; w < 16; ++w) { sst += rs[w]; llt += rl[w]; }
        double invn = 1.0 / (double)NPIX;
        out[0] = (float)(llt * invn + (1.0 - sst * invn));
    }
}

extern "C" void kernel_launch(void* const* d_in, const int* in_sizes, int n_in,
                              void* d_out, int out_size, void* d_ws, size_t ws_size,
                              hipStream_t stream) {
    const float* x = (const float*)d_in[0];   // outputs
    const float* y = (const float*)d_in[1];   // labels
    float* out = (float*)d_out;
    float* partials = (float*)d_ws;           // 2*NBLOCKS*4 = 49,152 B

    dim3 grid(NTX, NTY, NIMG);
    ssim_tile_kernel<<<grid, dim3(256), 0, stream>>>(x, y, partials);
    finalize_kernel<<<1, dim3(1024), 0, stream>>>(partials, out);
}

// Round 4
// 137.875 us; speedup vs baseline: 1.1809x; 1.1809x over previous
//
#include <hip/hip_runtime.h>
#include <hip/hip_bf16.h>
#include <math.h>

#define IMG 512
#define TW 64                     // output tile width
#define TH 32                     // output tile height
#define NTX 8                     // 512/64
#define NTY 16                    // 512/32
#define NIMG 48                   // 16*3
#define NBLOCKS (NTX * NTY * NIMG)   // 6144
#define NPIX (16LL * 3 * 512 * 512)

#define C1F 0.0001f
#define C2F 0.0009f

// R4: direct-from-global fragments (no LDS staging, no phase convoy — R3
// showed +50% memory duty cycle), with FULL SCALARIZATION of all H-conv
// results into 12 named uint2v registers. R3's `uint2v d1[3][4]` was lowered
// to scratch (VGPR_Count=40 < live set; WRITE_SIZE 74 MB of scratch stores,
// +37 MB scratch read misses) — rule #20. No indexed arrays remain on any
// hot path. launch_bounds(256,5): VGPR cap ~96 >> ~70 live, so the
// allocator never needs to spill.

typedef __attribute__((ext_vector_type(4))) short short4v;
typedef __attribute__((ext_vector_type(8))) short short8;
typedef __attribute__((ext_vector_type(4))) float float4v;
typedef __attribute__((ext_vector_type(2))) unsigned uint2v;
typedef __attribute__((ext_vector_type(4))) unsigned uint4v;

// 16x16x16 bf16 MFMA (device-verified _1k builtin on gfx950; host parse stub).
__device__ __forceinline__ float4v mfma16(short4v a, short4v b, float4v c) {
#if defined(__HIP_DEVICE_COMPILE__)
    return __builtin_amdgcn_mfma_f32_16x16x16bf16_1k(a, b, c, 0, 0, 0);
#else
    return c;   // host stub — never executed
#endif
}

// Gaussian window (sigma=1.5, ws=11), normalized (double-derived literals).
#define GW0 0.00102838f
#define GW1 0.00759877f
#define GW2 0.03600077f
#define GW3 0.10936069f
#define GW4 0.21300539f
#define GW5 0.26601172f

__device__ __forceinline__ unsigned short f2bf(float f) {
    unsigned u = __builtin_bit_cast(unsigned, f);
    u += 0x7FFF + ((u >> 16) & 1);            // RNE
    return (unsigned short)(u >> 16);
}
__device__ __forceinline__ unsigned pk2(float a, float b) {
    __hip_bfloat162 h = __float22bfloat162_rn(make_float2(a, b));
    unsigned u;
    __builtin_memcpy(&u, &h, 4);
    return u;
}

#define BC4(U) __builtin_bit_cast(short4v, U)

// One rg block: predicated 4x16B loads, in-register bf16 channel build,
// 4 H-conv MFMAs into named uint2v destinations, owned-region L1.
#define HCONV_RG(SROW_EXPR, ROW_EXPR, DSTX, DSTY, DSTS, DSTP)                  \
    {                                                                          \
        const int srow_ = (SROW_EXPR);                                         \
        const int gr_   = r00 + (ROW_EXPR);                                    \
        const bool ok_  = colok && (unsigned)gr_ < 512u;                       \
        float4 xf0 = zf, xf1 = zf, yf0 = zf, yf1 = zf;                         \
        if (ok_) {                                                             \
            const size_t o_ = (size_t)gr_ * IMG + cbase;                       \
            xf0 = *(const float4*)(xi + o_);                                   \
            xf1 = *(const float4*)(xi + o_ + 4);                               \
            yf0 = *(const float4*)(yi + o_);                                   \
            yf1 = *(const float4*)(yi + o_ + 4);                               \
        }                                                                      \
        uint4v ux_ = (uint4v){pk2(xf0.x, xf0.y), pk2(xf0.z, xf0.w),            \
                              pk2(xf1.x, xf1.y), pk2(xf1.z, xf1.w)};           \
        uint4v uy_ = (uint4v){pk2(yf0.x, yf0.y), pk2(yf0.z, yf0.w),            \
                              pk2(yf1.x, yf1.y), pk2(yf1.z, yf1.w)};           \
        uint4v u2_ = (uint4v){                                                 \
            pk2(fmaf(xf0.x,xf0.x,yf0.x*yf0.x), fmaf(xf0.y,xf0.y,yf0.y*yf0.y)), \
            pk2(fmaf(xf0.z,xf0.z,yf0.z*yf0.z), fmaf(xf0.w,xf0.w,yf0.w*yf0.w)), \
            pk2(fmaf(xf1.x,xf1.x,yf1.x*yf1.x), fmaf(xf1.y,xf1.y,yf1.y*yf1.y)), \
            pk2(fmaf(xf1.z,xf1.z,yf1.z*yf1.z), fmaf(xf1.w,xf1.w,yf1.w*yf1.w))};\
        uint4v u3_ = (uint4v){                                                 \
            pk2(xf0.x*yf0.x, xf0.y*yf0.y), pk2(xf0.z*yf0.z, xf0.w*yf0.w),      \
            pk2(xf1.x*yf1.x, xf1.y*yf1.y), pk2(xf1.z*yf1.z, xf1.w*yf1.w)};     \
        float4v d_;                                                            \
        d_ = __builtin_amdgcn_mfma_f32_16x16x32_bf16(                          \
                 __builtin_bit_cast(short8, ux_), bh, zero4, 0, 0, 0);         \
        DSTX = (uint2v){pk2(d_[0], d_[1]), pk2(d_[2], d_[3])};                 \
        d_ = __builtin_amdgcn_mfma_f32_16x16x32_bf16(                          \
                 __builtin_bit_cast(short8, uy_), bh, zero4, 0, 0, 0);         \
        DSTY = (uint2v){pk2(d_[0], d_[1]), pk2(d_[2], d_[3])};                 \
        d_ = __builtin_amdgcn_mfma_f32_16x16x32_bf16(                          \
                 __builtin_bit_cast(short8, u2_), bh, zero4, 0, 0, 0);         \
        DSTS = (uint2v){pk2(d_[0], d_[1]), pk2(d_[2], d_[3])};                 \
        d_ = __builtin_amdgcn_mfma_f32_16x16x32_bf16(                          \
                 __builtin_bit_cast(short8, u3_), bh, zero4, 0, 0, 0);         \
        DSTP = (uint2v){pk2(d_[0], d_[1]), pk2(d_[2], d_[3])};                 \
        if ((unsigned)(q - 1) <= 1u && (unsigned)(srow_ - 5) <= 31u)           \
            l1_loc += fabsf(xf0.x-yf0.x)+fabsf(xf0.y-yf0.y)                    \
                    + fabsf(xf0.z-yf0.z)+fabsf(xf0.w-yf0.w)                    \
                    + fabsf(xf1.x-yf1.x)+fabsf(xf1.y-yf1.y)                    \
                    + fabsf(xf1.z-yf1.z)+fabsf(xf1.w-yf1.w);                   \
    }

// SSIM epilogue over one float4v set.
#define SSIM_ACC(M1, M2, EE, PP)                                               \
    _Pragma("unroll")                                                          \
    for (int r_ = 0; r_ < 4; ++r_) {                                           \
        float mu1 = (M1)[r_], mu2 = (M2)[r_];                                  \
        float e   = (EE)[r_], e12 = (PP)[r_];                                  \
        float p = mu1 * mu2;                                                   \
        float s = fmaf(mu1, mu1, mu2 * mu2);                                   \
        float num1 = fmaf(2.f, p, C1F);                                        \
        float num2 = fmaf(2.f, e12 - p, C2F);                                  \
        float den1 = s + C1F;                                                  \
        float den2 = (e - s) + C2F;                                            \
        ssim_loc = fmaf(num1 * num2,                                           \
                        __builtin_amdgcn_rcpf(den1 * den2), ssim_loc);         \
    }

__global__ __launch_bounds__(256, 5)
void ssim_tile_kernel(const float* __restrict__ xg, const float* __restrict__ yg,
                      float* __restrict__ partials) {
    __shared__ unsigned short gwtbl[16];            // bf16 taps, [11..15]=0
    __shared__ float red[8];

    const int tid  = threadIdx.x;
    const int lane = tid & 63;
    const int w    = tid >> 6;        // wave 0..3 = colgroup
    const int q    = lane >> 4;       // quad 0..3
    const int n16  = lane & 15;

    const int img = blockIdx.z;
    const int r00  = blockIdx.y * TH - 5;   // global row of staged-coords row 0
    const int c00a = blockIdx.x * TW - 8;   // global col of staged-coords col 0
    const float* __restrict__ xi = xg + (size_t)img * (IMG * IMG);
    const float* __restrict__ yi = yg + (size_t)img * (IMG * IMG);

    // ---- bf16 Gaussian tap table (compile-time-folded constants) ----
    if (tid < 16) {
        const float gwf[11] = {GW0, GW1, GW2, GW3, GW4, GW5, GW4, GW3, GW2, GW1, GW0};
        unsigned short v = 0;
        #pragma unroll
        for (int t = 0; t < 11; ++t)
            if (tid == t) v = f2bf(gwf[t]);
        gwtbl[tid] = v;
    }
    __syncthreads();   // publish gwtbl (no memory in flight yet)

    // ---- B fragments from gwtbl (OOB index clamps to >=11 -> 0) ----
    // h (K=32): Bh[k][n] = g[k-n-3], k = q*8+j
    // v chunk0 (K=16): Bv0[k][n] = g[k-n]; chunk1: Bv1[k][n] = g[k+16-n]
    short8 bh;
    short4v bv0, bv1;
    {
        int baseh = q * 8 - n16 - 3;
        #pragma unroll
        for (int j = 0; j < 8; ++j)
            bh[j] = (short)gwtbl[min((unsigned)(baseh + j), 15u)];
        int base0 = q * 4 - n16, base1 = q * 4 + 16 - n16;
        #pragma unroll
        for (int j = 0; j < 4; ++j) {
            bv0[j] = (short)gwtbl[min((unsigned)(base0 + j), 15u)];
            bv1[j] = (short)gwtbl[min((unsigned)(base1 + j), 15u)];
        }
    }

    // ---- H-conv, fragments direct from global ----
    // Lane (w,q,n16), rg: 8 pixels at (r00+row, c00a+16w+8q+[0,8)).
    // rg=2 rows clamp to 41 (rows 42..47 feed only zero v-taps).
    const int cbase = c00a + w * 16 + q * 8;
    const bool colok = (unsigned)cbase < 512u;
    const float4v zero4 = {0.f, 0.f, 0.f, 0.f};
    const float4 zf = make_float4(0.f, 0.f, 0.f, 0.f);

    float l1_loc = 0.f;
    uint2v d0x, d0y, d0s, d0p;     // rg0: hconv of x, y, x^2+y^2, x*y
    uint2v e1x, e1y, e1s, e1p;     // rg1
    uint2v f2x, f2y, f2s, f2p;     // rg2

    HCONV_RG(n16,            n16,                 d0x, d0y, d0s, d0p)
    HCONV_RG(16 + n16,       16 + n16,            e1x, e1y, e1s, e1p)
    HCONV_RG(32 + n16,       min(32 + n16, 41),   f2x, f2y, f2s, f2p)

    // ---- V-conv: acc = D1[rgp]·Bv0 + D1[rgp+1]·Bv1 (chained x16 MFMAs).
    //      Output: lane (q,n16) = out row rgp*16+n16, out cols w*16+q*4+r. ----
    float ssim_loc = 0.f;
    {   // rgp = 0
        float4v am1 = mfma16(BC4(d0x), bv0, mfma16(BC4(e1x), bv1, zero4));
        float4v am2 = mfma16(BC4(d0y), bv0, mfma16(BC4(e1y), bv1, zero4));
        float4v ae  = mfma16(BC4(d0s), bv0, mfma16(BC4(e1s), bv1, zero4));
        float4v ap  = mfma16(BC4(d0p), bv0, mfma16(BC4(e1p), bv1, zero4));
        SSIM_ACC(am1, am2, ae, ap)
    }
    {   // rgp = 1
        float4v bm1 = mfma16(BC4(e1x), bv0, mfma16(BC4(f2x), bv1, zero4));
        float4v bm2 = mfma16(BC4(e1y), bv0, mfma16(BC4(f2y), bv1, zero4));
        float4v be  = mfma16(BC4(e1s), bv0, mfma16(BC4(f2s), bv1, zero4));
        float4v bp  = mfma16(BC4(e1p), bv0, mfma16(BC4(f2p), bv1, zero4));
        SSIM_ACC(bm1, bm2, be, bp)
    }

    // ---- Block reduction ----
    #pragma unroll
    for (int off = 32; off > 0; off >>= 1) {
        ssim_loc += __shfl_down(ssim_loc, off);
        l1_loc   += __shfl_down(l1_loc, off);
    }
    if (lane == 0) {
        red[w] = ssim_loc;
        red[4 + w] = l1_loc;
    }
    __syncthreads();
    if (tid == 0) {
        float ss = red[0] + red[1] + red[2] + red[3];
        float ll = red[4] + red[5] + red[6] + red[7];
        int bid = blockIdx.x + NTX * (blockIdx.y + NTY * blockIdx.z);
        partials[bid] = ss;
        partials[NBLOCKS + bid] = ll;
    }
}

__global__ __launch_bounds__(1024)
void finalize_kernel(const float* __restrict__ partials, float* __restrict__ out) {
    __shared__ double rs[16], rl[16];
    const int tid = threadIdx.x;
    double ss = 0.0, ll = 0.0;
    for (int i = tid; i < NBLOCKS; i += 1024) {
        ss += (double)partials[i];
        ll += (double)partials[NBLOCKS + i];
    }
    #pragma unroll
    for (int off = 32; off > 0; off >>= 1) {
        ss += __shfl_down(ss, off);
        ll += __shfl_down(ll, off);
    }
    int wave = tid >> 6, lane = tid & 63;
    if (lane == 0) { rs[wave] = ss; rl[wave] = ll; }
    __syncthreads();
    if (tid == 0) {
        double sst = 0.0, llt = 0.0;
        #pragma unroll
        for (int w = 0; w < 16; ++w) { sst += rs[w]; llt += rl[w]; }
        double invn = 1.0 / (double)NPIX;
        out[0] = (float)(llt * invn + (1.0 - sst * invn));
    }
}

extern "C" void kernel_launch(void* const* d_in, const int* in_sizes, int n_in,
                              void* d_out, int out_size, void* d_ws, size_t ws_size,
                              hipStream_t stream) {
    const float* x = (const float*)d_in[0];   // outputs
    const float* y = (const float*)d_in[1];   // labels
    float* out = (float*)d_out;
    float* partials = (float*)d_ws;           // 2*NBLOCKS*4 = 49,152 B

    dim3 grid(NTX, NTY, NIMG);
    ssim_tile_kernel<<<grid, dim3(256), 0, stream>>>(x, y, partials);
    finalize_kernel<<<1, dim3(1024), 0, stream>>>(partials, out);
}